// Round 1
// baseline (750.906 us; speedup 1.0000x reference)
//
#include <hip/hip_runtime.h>
#include <cstdint>
#include <cstddef>

#define Bn   128
#define Rn   500
#define Nn   500
#define Kn   10
#define En   128
#define H1n  640
#define KEn  1280
#define Mn   (Bn * Rn)   // 64000 rows

typedef short s16x8 __attribute__((ext_vector_type(8)));
typedef float f32x4 __attribute__((ext_vector_type(4)));

// fp32 -> bf16 round-to-nearest-even (inputs are finite; no NaN handling needed)
__device__ __forceinline__ unsigned short f2bf(float x) {
    union { float f; unsigned int u; } v; v.f = x;
    unsigned int r = v.u + 0x7fffu + ((v.u >> 16) & 1u);
    return (unsigned short)(r >> 16);
}

// ---------------- kernel 1: weights fp32 -> bf16 ----------------
__global__ void convw_kernel(const float* __restrict__ w1, const float* __restrict__ w2,
                             unsigned short* __restrict__ w1b, unsigned short* __restrict__ w2b) {
    int i = blockIdx.x * 256 + threadIdx.x;
    if (i < H1n * KEn) w1b[i] = f2bf(w1[i]);
    if (i < En * H1n)  w2b[i] = f2bf(w2[i]);
}

// ---------------- kernel 2: top-K smallest unvisited distances ----------------
// one wave (64 threads) per (b,r) row. Reproduces jax.lax.top_k(-dist) ordering:
// ascending distance, stable (smaller index wins ties). +inf winner => pad idx N.
__global__ void topk_kernel(const int* __restrict__ current,
                            const float* __restrict__ distance,
                            const float* __restrict__ masked,
                            int* __restrict__ idx_out) {
    const int row  = blockIdx.x;          // 0..63999
    const int lane = threadIdx.x;         // 0..63
    const int b    = row / Rn;
    const int cur  = current[row];
    const float* drow = distance + ((size_t)b * Nn + cur) * Nn;
    const float* mrow = masked + (size_t)row * Nn;

    float v[8];
    int   n[8];
#pragma unroll
    for (int i = 0; i < 8; ++i) {
        int nn = lane + 64 * i;
        n[i] = nn;
        if (nn < Nn) {
            float m = mrow[nn];
            float d = drow[nn];
            v[i] = (m == -INFINITY) ? INFINITY : d;   // visited -> +inf
        } else {
            v[i] = INFINITY;
        }
    }

    for (int it = 0; it < Kn; ++it) {
        float bv = INFINITY; int bn = 0x7fffffff;
#pragma unroll
        for (int i = 0; i < 8; ++i) {
            if (v[i] < bv || (v[i] == bv && n[i] < bn)) { bv = v[i]; bn = n[i]; }
        }
#pragma unroll
        for (int off = 1; off < 64; off <<= 1) {
            float ov = __shfl_xor(bv, off);
            int   on = __shfl_xor(bn, off);
            if (ov < bv || (ov == bv && on < bn)) { bv = ov; bn = on; }
        }
        if (lane == 0) idx_out[row * Kn + it] = (bv == INFINITY) ? Nn : bn;
        // knock out the winner everywhere it lives
#pragma unroll
        for (int i = 0; i < 8; ++i) {
            if (n[i] == bn) v[i] = INFINITY;
        }
    }
}

// ---------------- kernel 3: pad-avg mean vector per row ----------------
// mean[row][e] = sum_{k: idx<N} encoded[b, idx_k, e] / count  (0 if count==0)
__global__ void mean_kernel(const float* __restrict__ encoded,
                            const int* __restrict__ idx,
                            float* __restrict__ meanb) {
    const int row = blockIdx.x;
    const int e   = threadIdx.x;          // 0..127
    const int b   = row / Rn;
    float s = 0.f; int cnt = 0;
#pragma unroll
    for (int k = 0; k < Kn; ++k) {
        int id = idx[row * Kn + k];
        if (id < Nn) { s += encoded[((size_t)(b * Nn + id)) * En + e]; cnt++; }
    }
    meanb[(size_t)row * En + e] = (cnt > 0) ? (s / (float)cnt) : 0.f;
}

// ---------------- kernel 4: GEMM1 with fused gather ----------------
// C[m,h] = relu( sum_kk A[m,kk]*w1[h,kk] + b1[h] ), A gathered on the fly.
// Block: 256 thr = 4 waves, tile 128(M) x 128(H) x 64(K). 20 K-iterations.
#define LDSTRIDE 72
__global__ __launch_bounds__(256) void gemm1_kernel(
        const float* __restrict__ encoded, const float* __restrict__ meanb,
        const int* __restrict__ idxb, const unsigned short* __restrict__ w1b,
        const float* __restrict__ b1, unsigned short* __restrict__ hbuf) {
    __shared__ alignas(16) unsigned short As[128 * LDSTRIDE];
    __shared__ alignas(16) unsigned short Bs[128 * LDSTRIDE];

    const int t    = threadIdx.x;
    const int lane = t & 63;
    const int wave = t >> 6;
    const int wm   = wave & 1;        // wave's 64-row half
    const int wn   = wave >> 1;       // wave's 64-col half
    const int ln15 = lane & 15;
    const int q4   = lane >> 4;

    const int row0 = blockIdx.x * 128;
    const int h0   = blockIdx.y * 128;

    // staging mapping: 2 threads per row, 32 elements each
    const int rowL = t >> 1;
    const int hf   = t & 1;
    const int gRow = row0 + rowL;
    const int bb_  = gRow / Rn;

    f32x4 acc[4][4];
#pragma unroll
    for (int i = 0; i < 4; ++i)
#pragma unroll
        for (int j = 0; j < 4; ++j)
            acc[i][j] = (f32x4){0.f, 0.f, 0.f, 0.f};

    for (int itk = 0; itk < KEn / 64; ++itk) {
        const int kk0 = itk * 64;
        // ---- stage A (gather + cvt) ----
        {
            const int j  = kk0 >> 7;        // neighbor slot
            const int e0 = kk0 & 127;       // 0 or 64
            const int id = idxb[gRow * Kn + j];
            const float* src = (id < Nn)
                ? (encoded + ((size_t)(bb_ * Nn + id)) * En + e0)
                : (meanb + (size_t)gRow * En + e0);
            const float4* s4 = (const float4*)src;
#pragma unroll
            for (int q = 0; q < 8; ++q) {
                float4 vv = s4[hf * 8 + q];
                ushort4 o;
                o.x = f2bf(vv.x); o.y = f2bf(vv.y); o.z = f2bf(vv.z); o.w = f2bf(vv.w);
                *(ushort4*)&As[rowL * LDSTRIDE + hf * 32 + q * 4] = o;
            }
        }
        // ---- stage B (w1 bf16, contiguous) ----
        {
            const unsigned short* srcB = w1b + (size_t)(h0 + rowL) * KEn + kk0 + hf * 32;
#pragma unroll
            for (int q = 0; q < 4; ++q) {
                uint4 vv = ((const uint4*)srcB)[q];
                *(uint4*)&Bs[rowL * LDSTRIDE + hf * 32 + q * 8] = vv;
            }
        }
        __syncthreads();
        // ---- MFMA ----
#pragma unroll
        for (int kt = 0; kt < 2; ++kt) {
            s16x8 af[4], bf[4];
#pragma unroll
            for (int i = 0; i < 4; ++i)
                af[i] = *(const s16x8*)&As[(wm * 64 + i * 16 + ln15) * LDSTRIDE + kt * 32 + q4 * 8];
#pragma unroll
            for (int j = 0; j < 4; ++j)
                bf[j] = *(const s16x8*)&Bs[(wn * 64 + j * 16 + ln15) * LDSTRIDE + kt * 32 + q4 * 8];
#pragma unroll
            for (int i = 0; i < 4; ++i)
#pragma unroll
                for (int j = 0; j < 4; ++j)
                    acc[i][j] = __builtin_amdgcn_mfma_f32_16x16x32_bf16(af[i], bf[j], acc[i][j], 0, 0, 0);
        }
        __syncthreads();
    }

    // ---- epilogue: bias + relu + bf16 store ----
#pragma unroll
    for (int i = 0; i < 4; ++i) {
#pragma unroll
        for (int j = 0; j < 4; ++j) {
            const int nn = wn * 64 + j * 16 + ln15;
            const int h  = h0 + nn;
            const float bias = b1[h];
#pragma unroll
            for (int rg = 0; rg < 4; ++rg) {
                const int m = wm * 64 + i * 16 + q4 * 4 + rg;
                float vv = acc[i][j][rg] + bias;
                vv = fmaxf(vv, 0.f);
                hbuf[(size_t)(row0 + m) * H1n + h] = f2bf(vv);
            }
        }
    }
}

// ---------------- kernel 5: GEMM2 ----------------
// out[m,e] = sum_h hbuf[m,h]*w2[e,h] + b2[e]. Tile 128x128x64, 10 K-iters.
__global__ __launch_bounds__(256) void gemm2_kernel(
        const unsigned short* __restrict__ hbuf, const unsigned short* __restrict__ w2b,
        const float* __restrict__ b2, float* __restrict__ out) {
    __shared__ alignas(16) unsigned short As[128 * LDSTRIDE];
    __shared__ alignas(16) unsigned short Bs[128 * LDSTRIDE];

    const int t    = threadIdx.x;
    const int lane = t & 63;
    const int wave = t >> 6;
    const int wm   = wave & 1;
    const int wn   = wave >> 1;
    const int ln15 = lane & 15;
    const int q4   = lane >> 4;

    const int row0 = blockIdx.x * 128;
    const int rowL = t >> 1;
    const int hf   = t & 1;

    f32x4 acc[4][4];
#pragma unroll
    for (int i = 0; i < 4; ++i)
#pragma unroll
        for (int j = 0; j < 4; ++j)
            acc[i][j] = (f32x4){0.f, 0.f, 0.f, 0.f};

    for (int itk = 0; itk < H1n / 64; ++itk) {
        const int kk0 = itk * 64;
        {
            const unsigned short* srcA = hbuf + (size_t)(row0 + rowL) * H1n + kk0 + hf * 32;
#pragma unroll
            for (int q = 0; q < 4; ++q) {
                uint4 vv = ((const uint4*)srcA)[q];
                *(uint4*)&As[rowL * LDSTRIDE + hf * 32 + q * 8] = vv;
            }
        }
        {
            const unsigned short* srcB = w2b + (size_t)rowL * H1n + kk0 + hf * 32;
#pragma unroll
            for (int q = 0; q < 4; ++q) {
                uint4 vv = ((const uint4*)srcB)[q];
                *(uint4*)&Bs[rowL * LDSTRIDE + hf * 32 + q * 8] = vv;
            }
        }
        __syncthreads();
#pragma unroll
        for (int kt = 0; kt < 2; ++kt) {
            s16x8 af[4], bf[4];
#pragma unroll
            for (int i = 0; i < 4; ++i)
                af[i] = *(const s16x8*)&As[(wm * 64 + i * 16 + ln15) * LDSTRIDE + kt * 32 + q4 * 8];
#pragma unroll
            for (int j = 0; j < 4; ++j)
                bf[j] = *(const s16x8*)&Bs[(wn * 64 + j * 16 + ln15) * LDSTRIDE + kt * 32 + q4 * 8];
#pragma unroll
            for (int i = 0; i < 4; ++i)
#pragma unroll
                for (int j = 0; j < 4; ++j)
                    acc[i][j] = __builtin_amdgcn_mfma_f32_16x16x32_bf16(af[i], bf[j], acc[i][j], 0, 0, 0);
        }
        __syncthreads();
    }

#pragma unroll
    for (int i = 0; i < 4; ++i) {
#pragma unroll
        for (int j = 0; j < 4; ++j) {
            const int e = wn * 64 + j * 16 + ln15;   // 0..127
            const float bias = b2[e];
#pragma unroll
            for (int rg = 0; rg < 4; ++rg) {
                const int m = wm * 64 + i * 16 + q4 * 4 + rg;
                out[(size_t)(row0 + m) * En + e] = acc[i][j][rg] + bias;
            }
        }
    }
}

// ---------------- launch ----------------
extern "C" void kernel_launch(void* const* d_in, const int* in_sizes, int n_in,
                              void* d_out, int out_size, void* d_ws, size_t ws_size,
                              hipStream_t stream) {
    const int*   current  = (const int*)d_in[0];
    const float* distance = (const float*)d_in[1];
    const float* masked   = (const float*)d_in[2];
    const float* encoded  = (const float*)d_in[3];
    const float* w1       = (const float*)d_in[4];
    const float* b1       = (const float*)d_in[5];
    const float* w2       = (const float*)d_in[6];
    const float* b2       = (const float*)d_in[7];
    float* out = (float*)d_out;

    char* ws = (char*)d_ws;
    // workspace layout (all 256B aligned)
    const size_t OFF_IDX  = 0;                          // 64000*10*4   = 2,560,000
    const size_t OFF_MEAN = 2560000;                    // 64000*128*4  = 32,768,000
    const size_t OFF_W1B  = OFF_MEAN + 32768000;        // 640*1280*2   = 1,638,400
    const size_t OFF_W2B  = OFF_W1B + 1638400;          // 128*640*2    = 163,840
    const size_t OFF_H    = OFF_W2B + 163840;           // 64000*640*2  = 81,920,000
    int*            idxb  = (int*)(ws + OFF_IDX);
    float*          meanb = (float*)(ws + OFF_MEAN);
    unsigned short* w1b   = (unsigned short*)(ws + OFF_W1B);
    unsigned short* w2b   = (unsigned short*)(ws + OFF_W2B);
    unsigned short* hbuf  = (unsigned short*)(ws + OFF_H);

    convw_kernel<<<(H1n * KEn + 255) / 256, 256, 0, stream>>>(w1, w2, w1b, w2b);
    topk_kernel<<<Mn, 64, 0, stream>>>(current, distance, masked, idxb);
    mean_kernel<<<Mn, En, 0, stream>>>(encoded, idxb, meanb);
    gemm1_kernel<<<dim3(Mn / 128, H1n / 128), 256, 0, stream>>>(encoded, meanb, idxb, w1b, b1, hbuf);
    gemm2_kernel<<<Mn / 128, 256, 0, stream>>>(hbuf, w2b, b2, out);
}

// Round 2
// 649.991 us; speedup vs baseline: 1.1553x; 1.1553x over previous
//
#include <hip/hip_runtime.h>
#include <cstdint>
#include <cstddef>

#define Bn   128
#define Rn   500
#define Nn   500
#define Kn   10
#define En   128
#define H1n  640
#define KEn  1280
#define Mn   (Bn * Rn)   // 64000 rows

typedef short s16x8 __attribute__((ext_vector_type(8)));
typedef float f32x4 __attribute__((ext_vector_type(4)));

// fp32 -> bf16 round-to-nearest-even (finite inputs)
__device__ __forceinline__ unsigned short f2bf(float x) {
    union { float f; unsigned int u; } v; v.f = x;
    unsigned int r = v.u + 0x7fffu + ((v.u >> 16) & 1u);
    return (unsigned short)(r >> 16);
}
__device__ __forceinline__ float bf2f(unsigned short u) {
    union { unsigned int u; float f; } v; v.u = ((unsigned int)u) << 16;
    return v.f;
}
// async 16B global->LDS (wave-uniform LDS base + lane*16)
__device__ __forceinline__ void gl2lds16(const void* g, void* l) {
    __builtin_amdgcn_global_load_lds(
        (const __attribute__((address_space(1))) unsigned int*)g,
        (__attribute__((address_space(3))) unsigned int*)l, 16, 0, 0);
}

// ---------------- kernel 1: fp32 -> bf16 conversions (encoded, w1, w2) ----------------
__global__ void convw_kernel(const float* __restrict__ enc, const float* __restrict__ w1,
                             const float* __restrict__ w2,
                             unsigned short* __restrict__ encb, unsigned short* __restrict__ w1b,
                             unsigned short* __restrict__ w2b) {
    int i = blockIdx.x * 256 + threadIdx.x;   // float4 group index
    if (i < (Bn * Nn * En) / 4) {
        float4 v = ((const float4*)enc)[i];
        ushort4 o; o.x = f2bf(v.x); o.y = f2bf(v.y); o.z = f2bf(v.z); o.w = f2bf(v.w);
        ((ushort4*)encb)[i] = o;
    }
    if (i < (H1n * KEn) / 4) {
        float4 v = ((const float4*)w1)[i];
        ushort4 o; o.x = f2bf(v.x); o.y = f2bf(v.y); o.z = f2bf(v.z); o.w = f2bf(v.w);
        ((ushort4*)w1b)[i] = o;
    }
    if (i < (En * H1n) / 4) {
        float4 v = ((const float4*)w2)[i];
        ushort4 o; o.x = f2bf(v.x); o.y = f2bf(v.y); o.z = f2bf(v.z); o.w = f2bf(v.w);
        ((ushort4*)w2b)[i] = o;
    }
}

// ---------------- kernel 2: top-K smallest unvisited distances ----------------
// 4 waves/block, one wave per (b,r) row. Stable ascending order, +inf -> pad idx N.
__global__ __launch_bounds__(256) void topk_kernel(const int* __restrict__ current,
                            const float* __restrict__ distance,
                            const float* __restrict__ masked,
                            int* __restrict__ idx_out) {
    const int row  = blockIdx.x * 4 + (threadIdx.x >> 6);
    const int lane = threadIdx.x & 63;
    const int b    = row / Rn;
    const int cur  = current[row];
    const float* drow = distance + ((size_t)b * Nn + cur) * Nn;
    const float* mrow = masked + (size_t)row * Nn;

    float v[8];
    int   n[8];
#pragma unroll
    for (int i = 0; i < 8; ++i) {
        int nn = lane + 64 * i;
        n[i] = nn;
        if (nn < Nn) {
            float m = mrow[nn];
            float d = drow[nn];
            v[i] = (m == -INFINITY) ? INFINITY : d;
        } else {
            v[i] = INFINITY;
        }
    }
    for (int it = 0; it < Kn; ++it) {
        float bv = INFINITY; int bn = 0x7fffffff;
#pragma unroll
        for (int i = 0; i < 8; ++i) {
            if (v[i] < bv || (v[i] == bv && n[i] < bn)) { bv = v[i]; bn = n[i]; }
        }
#pragma unroll
        for (int off = 1; off < 64; off <<= 1) {
            float ov = __shfl_xor(bv, off);
            int   on = __shfl_xor(bn, off);
            if (ov < bv || (ov == bv && on < bn)) { bv = ov; bn = on; }
        }
        if (lane == 0) idx_out[row * Kn + it] = (bv == INFINITY) ? Nn : bn;
#pragma unroll
        for (int i = 0; i < 8; ++i) {
            if (n[i] == bn) v[i] = INFINITY;
        }
    }
}

// ---------------- kernel 3: pad-avg mean vector per row (bf16 in/out) ----------------
__global__ __launch_bounds__(256) void mean_kernel(const unsigned short* __restrict__ encb,
                            const int* __restrict__ idx,
                            unsigned short* __restrict__ meanbb) {
    const int row = blockIdx.x * 2 + (threadIdx.x >> 7);
    const int e   = threadIdx.x & 127;
    const int b   = row / Rn;
    float s = 0.f; int cnt = 0;
#pragma unroll
    for (int k = 0; k < Kn; ++k) {
        int id = idx[row * Kn + k];
        if (id < Nn) { s += bf2f(encb[((size_t)(b * Nn + id)) * En + e]); cnt++; }
    }
    meanbb[(size_t)row * En + e] = f2bf((cnt > 0) ? (s / (float)cnt) : 0.f);
}

// ---------------- kernel 4: GEMM1 with fused gather (async LDS staging) ----------------
// C[m,h] = relu( sum A[m,:]*w1[h,:] + b1[h] ). Tile 128x128x64, XOR-swizzled LDS.
__global__ __launch_bounds__(256) void gemm1_kernel(
        const unsigned short* __restrict__ encb, const unsigned short* __restrict__ meanbb,
        const int* __restrict__ idxb, const unsigned short* __restrict__ w1b,
        const float* __restrict__ b1, unsigned short* __restrict__ hbuf) {
    __shared__ alignas(16) unsigned short As[128 * 64];   // 16 KB, swizzled
    __shared__ alignas(16) unsigned short Bs[128 * 64];   // 16 KB, swizzled

    // XCD-aware logical remap: 5 h-blocks of the same m-block run consecutively
    // on the same XCD (assumed xcd = blockIdx.x % 8) for A-gather L2 reuse.
    const int p = blockIdx.x;
    const int L = (p & 7) * 313 + (p >> 3);
    if (L >= (Mn / 128) * (H1n / 128)) return;
    const int row0 = (L / 5) * 128;
    const int h0   = (L % 5) * 128;

    const int t    = threadIdx.x;
    const int lane = t & 63;
    const int wave = t >> 6;
    const int ln15 = lane & 15;
    const int q4   = lane >> 4;
    const int wm   = wave & 1;
    const int wn   = wave >> 1;

    // staging geometry: each wave covers 32 rows (4 instrs x 8 rows), lane -> (row, chunk)
    const int rl   = lane >> 3;          // row within 8-row group
    const int sc   = lane & 7;           // swizzled 16B-slot
    const int coff = (sc ^ rl) * 8;      // source chunk offset (shorts), const across s/wave

    // precompute per-s row pointers
    const int* idxrow[4];
    const unsigned short* encbase[4];
    const unsigned short* meanrow[4];
    const unsigned short* w1row[4];
#pragma unroll
    for (int s = 0; s < 4; ++s) {
        const int lr = wave * 32 + s * 8 + rl;
        const int gr = row0 + lr;
        const int bb = gr / Rn;
        idxrow[s]  = idxb + (size_t)gr * Kn;
        encbase[s] = encb + (size_t)bb * Nn * En;
        meanrow[s] = meanbb + (size_t)gr * En + coff;
        w1row[s]   = w1b + (size_t)(h0 + lr) * KEn + coff;
    }

    f32x4 acc[4][4];
#pragma unroll
    for (int i = 0; i < 4; ++i)
#pragma unroll
        for (int j = 0; j < 4; ++j)
            acc[i][j] = (f32x4){0.f, 0.f, 0.f, 0.f};

    for (int itk = 0; itk < KEn / 64; ++itk) {
        const int kk0 = itk * 64;
        const int j   = itk >> 1;            // neighbor slot
        const int e0  = (itk & 1) * 64;      // half of the embedding
        // ---- async stage A (gathered) + B ----
#pragma unroll
        for (int s = 0; s < 4; ++s) {
            const int id = idxrow[s][j];
            const unsigned short* srcA = (id < Nn)
                ? (encbase[s] + (size_t)id * En + e0 + coff)
                : (meanrow[s] + e0);
            gl2lds16(srcA, &As[(wave * 32 + s * 8) * 64]);
        }
#pragma unroll
        for (int s = 0; s < 4; ++s) {
            gl2lds16(w1row[s] + kk0, &Bs[(wave * 32 + s * 8) * 64]);
        }
        __syncthreads();
        // ---- MFMA ----
#pragma unroll
        for (int kt = 0; kt < 2; ++kt) {
            s16x8 af[4], bf[4];
#pragma unroll
            for (int i = 0; i < 4; ++i)
                af[i] = *(const s16x8*)&As[(wm * 64 + i * 16 + ln15) * 64 + (((kt * 4 + q4) ^ (ln15 & 7)) * 8)];
#pragma unroll
            for (int jj = 0; jj < 4; ++jj)
                bf[jj] = *(const s16x8*)&Bs[(wn * 64 + jj * 16 + ln15) * 64 + (((kt * 4 + q4) ^ (ln15 & 7)) * 8)];
#pragma unroll
            for (int i = 0; i < 4; ++i)
#pragma unroll
                for (int jj = 0; jj < 4; ++jj)
                    acc[i][jj] = __builtin_amdgcn_mfma_f32_16x16x32_bf16(af[i], bf[jj], acc[i][jj], 0, 0, 0);
        }
        __syncthreads();
    }

    // ---- epilogue: bias + relu + bf16 store ----
#pragma unroll
    for (int i = 0; i < 4; ++i) {
#pragma unroll
        for (int jj = 0; jj < 4; ++jj) {
            const int h = h0 + wn * 64 + jj * 16 + ln15;
            const float bias = b1[h];
#pragma unroll
            for (int rg = 0; rg < 4; ++rg) {
                const int m = wm * 64 + i * 16 + q4 * 4 + rg;
                float vv = acc[i][jj][rg] + bias;
                vv = fmaxf(vv, 0.f);
                hbuf[(size_t)(row0 + m) * H1n + h] = f2bf(vv);
            }
        }
    }
}

// ---------------- kernel 5: GEMM2 (async LDS staging) ----------------
__global__ __launch_bounds__(256) void gemm2_kernel(
        const unsigned short* __restrict__ hbuf, const unsigned short* __restrict__ w2b,
        const float* __restrict__ b2, float* __restrict__ out) {
    __shared__ alignas(16) unsigned short As[128 * 64];
    __shared__ alignas(16) unsigned short Bs[128 * 64];

    const int row0 = blockIdx.x * 128;
    const int t    = threadIdx.x;
    const int lane = t & 63;
    const int wave = t >> 6;
    const int ln15 = lane & 15;
    const int q4   = lane >> 4;
    const int wm   = wave & 1;
    const int wn   = wave >> 1;

    const int rl   = lane >> 3;
    const int sc   = lane & 7;
    const int coff = (sc ^ rl) * 8;

    const unsigned short* hrow[4];
    const unsigned short* w2row[4];
#pragma unroll
    for (int s = 0; s < 4; ++s) {
        const int lr = wave * 32 + s * 8 + rl;
        hrow[s]  = hbuf + (size_t)(row0 + lr) * H1n + coff;
        w2row[s] = w2b + (size_t)lr * H1n + coff;
    }

    f32x4 acc[4][4];
#pragma unroll
    for (int i = 0; i < 4; ++i)
#pragma unroll
        for (int j = 0; j < 4; ++j)
            acc[i][j] = (f32x4){0.f, 0.f, 0.f, 0.f};

    for (int itk = 0; itk < H1n / 64; ++itk) {
        const int kk0 = itk * 64;
#pragma unroll
        for (int s = 0; s < 4; ++s)
            gl2lds16(hrow[s] + kk0, &As[(wave * 32 + s * 8) * 64]);
#pragma unroll
        for (int s = 0; s < 4; ++s)
            gl2lds16(w2row[s] + kk0, &Bs[(wave * 32 + s * 8) * 64]);
        __syncthreads();
#pragma unroll
        for (int kt = 0; kt < 2; ++kt) {
            s16x8 af[4], bf[4];
#pragma unroll
            for (int i = 0; i < 4; ++i)
                af[i] = *(const s16x8*)&As[(wm * 64 + i * 16 + ln15) * 64 + (((kt * 4 + q4) ^ (ln15 & 7)) * 8)];
#pragma unroll
            for (int jj = 0; jj < 4; ++jj)
                bf[jj] = *(const s16x8*)&Bs[(wn * 64 + jj * 16 + ln15) * 64 + (((kt * 4 + q4) ^ (ln15 & 7)) * 8)];
#pragma unroll
            for (int i = 0; i < 4; ++i)
#pragma unroll
                for (int jj = 0; jj < 4; ++jj)
                    acc[i][jj] = __builtin_amdgcn_mfma_f32_16x16x32_bf16(af[i], bf[jj], acc[i][jj], 0, 0, 0);
        }
        __syncthreads();
    }

#pragma unroll
    for (int i = 0; i < 4; ++i) {
#pragma unroll
        for (int jj = 0; jj < 4; ++jj) {
            const int e = wn * 64 + jj * 16 + ln15;
            const float bias = b2[e];
#pragma unroll
            for (int rg = 0; rg < 4; ++rg) {
                const int m = wm * 64 + i * 16 + q4 * 4 + rg;
                out[(size_t)(row0 + m) * En + e] = acc[i][jj][rg] + bias;
            }
        }
    }
}

// ---------------- launch ----------------
extern "C" void kernel_launch(void* const* d_in, const int* in_sizes, int n_in,
                              void* d_out, int out_size, void* d_ws, size_t ws_size,
                              hipStream_t stream) {
    const int*   current  = (const int*)d_in[0];
    const float* distance = (const float*)d_in[1];
    const float* masked   = (const float*)d_in[2];
    const float* encoded  = (const float*)d_in[3];
    const float* w1       = (const float*)d_in[4];
    const float* b1       = (const float*)d_in[5];
    const float* w2       = (const float*)d_in[6];
    const float* b2       = (const float*)d_in[7];
    float* out = (float*)d_out;

    char* ws = (char*)d_ws;
    const size_t OFF_IDX  = 0;                          // 64000*10*4   = 2,560,000
    const size_t OFF_ENCB = 2560000;                    // 8,192,000*2  = 16,384,000
    const size_t OFF_MEAN = OFF_ENCB + 16384000;        // 64000*128*2  = 16,384,000
    const size_t OFF_W1B  = OFF_MEAN + 16384000;        // 819200*2     = 1,638,400
    const size_t OFF_W2B  = OFF_W1B + 1638400;          // 81920*2      = 163,840
    const size_t OFF_H    = OFF_W2B + 163840;           // 64000*640*2  = 81,920,000
    int*            idxb   = (int*)(ws + OFF_IDX);
    unsigned short* encb   = (unsigned short*)(ws + OFF_ENCB);
    unsigned short* meanbb = (unsigned short*)(ws + OFF_MEAN);
    unsigned short* w1b    = (unsigned short*)(ws + OFF_W1B);
    unsigned short* w2b    = (unsigned short*)(ws + OFF_W2B);
    unsigned short* hbuf   = (unsigned short*)(ws + OFF_H);

    convw_kernel<<<(Bn * Nn * En / 4 + 255) / 256, 256, 0, stream>>>(encoded, w1, w2, encb, w1b, w2b);
    topk_kernel<<<Mn / 4, 256, 0, stream>>>(current, distance, masked, idxb);
    mean_kernel<<<Mn / 2, 256, 0, stream>>>(encb, idxb, meanbb);
    // grid = 8 * ceil(2500/8) = 2504 (4 no-op blocks)
    gemm1_kernel<<<2504, 256, 0, stream>>>(encb, meanbb, idxb, w1b, b1, hbuf);
    gemm2_kernel<<<Mn / 128, 256, 0, stream>>>(hbuf, w2b, b2, out);
}

// Round 4
// 555.822 us; speedup vs baseline: 1.3510x; 1.1694x over previous
//
#include <hip/hip_runtime.h>
#include <cstdint>
#include <cstddef>

#define Bn   128
#define Rn   500
#define Nn   500
#define Kn   10
#define En   128
#define H1n  640
#define KEn  1280
#define Mn   (Bn * Rn)   // 64000 rows

typedef short s16x8 __attribute__((ext_vector_type(8)));
typedef float f32x4 __attribute__((ext_vector_type(4)));

// fp32 -> bf16 round-to-nearest-even (finite inputs)
__device__ __forceinline__ unsigned short f2bf(float x) {
    union { float f; unsigned int u; } v; v.f = x;
    unsigned int r = v.u + 0x7fffu + ((v.u >> 16) & 1u);
    return (unsigned short)(r >> 16);
}
__device__ __forceinline__ float bf2f(unsigned short u) {
    union { unsigned int u; float f; } v; v.u = ((unsigned int)u) << 16;
    return v.f;
}
// async 16B global->LDS (wave-uniform LDS base + lane*16)
__device__ __forceinline__ void gl2lds16(const void* g, void* l) {
    __builtin_amdgcn_global_load_lds(
        (const __attribute__((address_space(1))) unsigned int*)g,
        (__attribute__((address_space(3))) unsigned int*)l, 16, 0, 0);
}
// explicit full drain: DMAs complete + LDS reads consumed BEFORE barrier arrival.
// The dbuf pipeline's correctness must not depend on the compiler's implicit
// barrier waits (R3 raced when warm).
__device__ __forceinline__ void drain_all() {
    asm volatile("s_waitcnt vmcnt(0) lgkmcnt(0)" ::: "memory");
}

// ---------------- kernel 1: fp32 -> bf16 conversions (encoded, w1, w2) ----------------
__global__ void convw_kernel(const float* __restrict__ enc, const float* __restrict__ w1,
                             const float* __restrict__ w2,
                             unsigned short* __restrict__ encb, unsigned short* __restrict__ w1b,
                             unsigned short* __restrict__ w2b) {
    int i = blockIdx.x * 256 + threadIdx.x;   // float4 group index
    if (i < (Bn * Nn * En) / 4) {
        float4 v = ((const float4*)enc)[i];
        ushort4 o; o.x = f2bf(v.x); o.y = f2bf(v.y); o.z = f2bf(v.z); o.w = f2bf(v.w);
        ((ushort4*)encb)[i] = o;
    }
    if (i < (H1n * KEn) / 4) {
        float4 v = ((const float4*)w1)[i];
        ushort4 o; o.x = f2bf(v.x); o.y = f2bf(v.y); o.z = f2bf(v.z); o.w = f2bf(v.w);
        ((ushort4*)w1b)[i] = o;
    }
    if (i < (En * H1n) / 4) {
        float4 v = ((const float4*)w2)[i];
        ushort4 o; o.x = f2bf(v.x); o.y = f2bf(v.y); o.z = f2bf(v.z); o.w = f2bf(v.w);
        ((ushort4*)w2b)[i] = o;
    }
}

// ---------------- kernel 2: top-K via u64 (bits(dist), idx) keys ----------------
__global__ __launch_bounds__(256) void topk_kernel(const int* __restrict__ current,
                            const float* __restrict__ distance,
                            const float* __restrict__ masked,
                            int* __restrict__ idx_out) {
    const int row  = blockIdx.x * 4 + (threadIdx.x >> 6);
    const int lane = threadIdx.x & 63;
    const int b    = row / Rn;
    const int cur  = current[row];
    const unsigned int* drow = (const unsigned int*)(distance + ((size_t)b * Nn + cur) * Nn);
    const unsigned int* mrow = (const unsigned int*)(masked + (size_t)row * Nn);

    unsigned long long key[8];
#pragma unroll
    for (int i = 0; i < 8; ++i) {
        int nn = lane + 64 * i;
        unsigned int fb = 0x7F800000u;            // +inf
        if (nn < Nn) {
            unsigned int m = mrow[nn];
            unsigned int d = drow[nn];
            fb = (m == 0xFF800000u) ? 0x7F800000u : d;   // visited -> +inf
        }
        key[i] = ((unsigned long long)fb << 32) | (unsigned int)nn;
    }
    for (int it = 0; it < Kn; ++it) {
        unsigned long long bk = key[0];
#pragma unroll
        for (int i = 1; i < 8; ++i) bk = (key[i] < bk) ? key[i] : bk;
#pragma unroll
        for (int off = 1; off < 64; off <<= 1) {
            unsigned long long ok = __shfl_xor(bk, off);
            bk = (ok < bk) ? ok : bk;
        }
        if (lane == 0) {
            int bn = (int)(bk & 0xffffffffu);
            idx_out[row * Kn + it] = ((bk >> 32) == 0x7F800000u) ? Nn : bn;
        }
#pragma unroll
        for (int i = 0; i < 8; ++i)
            if (key[i] == bk) key[i] = 0x7F800000FFFFFFFFull;  // knock out winner
    }
}

// ---------------- kernel 3: pad-avg mean vector per row (bf16 in/out) ----------------
__global__ __launch_bounds__(256) void mean_kernel(const unsigned short* __restrict__ encb,
                            const int* __restrict__ idx,
                            unsigned short* __restrict__ meanbb) {
    const int row = blockIdx.x * 2 + (threadIdx.x >> 7);
    const int e   = threadIdx.x & 127;
    const int b   = row / Rn;
    float s = 0.f; int cnt = 0;
#pragma unroll
    for (int k = 0; k < Kn; ++k) {
        int id = idx[row * Kn + k];
        if (id < Nn) { s += bf2f(encb[((size_t)(b * Nn + id)) * En + e]); cnt++; }
    }
    meanbb[(size_t)row * En + e] = f2bf((cnt > 0) ? (s / (float)cnt) : 0.f);
}

// ---------------- kernel 4: GEMM1, fused gather, double-buffered pipeline ----------------
// C[m,h] = relu( sum A[m,:]*w1[h,:] + b1[h] ). Tile 128x128x64; one barrier per
// K-iter, explicit vm/lgkm drain before each barrier (race-proof dbuf).
__global__ __launch_bounds__(256) void gemm1_kernel(
        const unsigned short* __restrict__ encb, const unsigned short* __restrict__ meanbb,
        const int* __restrict__ idxb, const unsigned short* __restrict__ w1b,
        const float* __restrict__ b1, unsigned short* __restrict__ hbuf) {
    __shared__ alignas(16) unsigned short As[2][128 * 64];   // 2 x 16 KB
    __shared__ alignas(16) unsigned short Bs[2][128 * 64];   // 2 x 16 KB
    __shared__ int idxs[128 * Kn];                           // 5 KB

    // XCD-aware remap: 5 h-blocks of one m-block consecutive per XCD.
    const int p = blockIdx.x;
    const int L = (p & 7) * 313 + (p >> 3);
    if (L >= (Mn / 128) * (H1n / 128)) return;
    const int row0 = (L / 5) * 128;
    const int h0   = (L % 5) * 128;

    const int t    = threadIdx.x;
    const int lane = t & 63;
    const int wave = t >> 6;
    const int ln15 = lane & 15;
    const int q4   = lane >> 4;
    const int wm   = wave & 1;
    const int wn   = wave >> 1;

    // stage idx tile (contiguous 1280 ints)
    for (int i = t; i < 128 * Kn; i += 256) idxs[i] = idxb[row0 * Kn + i];

    // staging geometry: lane -> (row-in-8-group, swizzled 16B slot)
    const int rl   = lane >> 3;
    const int sc   = lane & 7;
    const int coff = (sc ^ rl) * 8;       // source chunk offset (shorts)

    int lrow[4];
    const unsigned short* encB[4];
    const unsigned short* meanR[4];
    const unsigned short* w1R[4];
#pragma unroll
    for (int s = 0; s < 4; ++s) {
        lrow[s] = wave * 32 + s * 8 + rl;
        const int gr = row0 + lrow[s];
        const int bb = gr / Rn;
        encB[s]  = encb + (size_t)bb * Nn * En;
        meanR[s] = meanbb + (size_t)gr * En + coff;
        w1R[s]   = w1b + (size_t)(h0 + lrow[s]) * KEn + coff;
    }

    f32x4 acc[4][4];
#pragma unroll
    for (int i = 0; i < 4; ++i)
#pragma unroll
        for (int j = 0; j < 4; ++j)
            acc[i][j] = (f32x4){0.f, 0.f, 0.f, 0.f};

    auto issue = [&](int itk, int pb) {
        const int j   = itk >> 1;
        const int e0  = (itk & 1) * 64;
        const int kk0 = itk * 64;
#pragma unroll
        for (int s = 0; s < 4; ++s) {
            const int id = idxs[lrow[s] * Kn + j];
            const unsigned short* srcA = (id < Nn)
                ? (encB[s] + (size_t)id * En + e0 + coff)
                : (meanR[s] + e0);
            gl2lds16(srcA, &As[pb][(wave * 32 + s * 8) * 64]);
            gl2lds16(w1R[s] + kk0, &Bs[pb][(wave * 32 + s * 8) * 64]);
        }
    };

    drain_all();
    __syncthreads();          // idxs visible
    issue(0, 0);

    for (int itk = 0; itk < KEn / 64; ++itk) {
        const int cur = itk & 1;
        drain_all();          // my DMAs landed + my LDS reads consumed
        __syncthreads();      // everyone's landed/consumed
        if (itk + 1 < KEn / 64) issue(itk + 1, cur ^ 1);
#pragma unroll
        for (int kt = 0; kt < 2; ++kt) {
            s16x8 af[4], bf[4];
#pragma unroll
            for (int i = 0; i < 4; ++i)
                af[i] = *(const s16x8*)&As[cur][(wm * 64 + i * 16 + ln15) * 64 + (((kt * 4 + q4) ^ (ln15 & 7)) * 8)];
#pragma unroll
            for (int jj = 0; jj < 4; ++jj)
                bf[jj] = *(const s16x8*)&Bs[cur][(wn * 64 + jj * 16 + ln15) * 64 + (((kt * 4 + q4) ^ (ln15 & 7)) * 8)];
#pragma unroll
            for (int i = 0; i < 4; ++i)
#pragma unroll
                for (int jj = 0; jj < 4; ++jj)
                    acc[i][jj] = __builtin_amdgcn_mfma_f32_16x16x32_bf16(af[i], bf[jj], acc[i][jj], 0, 0, 0);
        }
    }

    // ---- epilogue: bias + relu + bf16 store ----
#pragma unroll
    for (int i = 0; i < 4; ++i) {
#pragma unroll
        for (int jj = 0; jj < 4; ++jj) {
            const int h = h0 + wn * 64 + jj * 16 + ln15;
            const float bias = b1[h];
#pragma unroll
            for (int rg = 0; rg < 4; ++rg) {
                const int m = wm * 64 + i * 16 + q4 * 4 + rg;
                float vv = acc[i][jj][rg] + bias;
                vv = fmaxf(vv, 0.f);
                hbuf[(size_t)(row0 + m) * H1n + h] = f2bf(vv);
            }
        }
    }
}

// ---------------- kernel 5: GEMM2, double-buffered pipeline ----------------
__global__ __launch_bounds__(256) void gemm2_kernel(
        const unsigned short* __restrict__ hbuf, const unsigned short* __restrict__ w2b,
        const float* __restrict__ b2, float* __restrict__ out) {
    __shared__ alignas(16) unsigned short As[2][128 * 64];
    __shared__ alignas(16) unsigned short Bs[2][128 * 64];

    const int row0 = blockIdx.x * 128;
    const int t    = threadIdx.x;
    const int lane = t & 63;
    const int wave = t >> 6;
    const int ln15 = lane & 15;
    const int q4   = lane >> 4;
    const int wm   = wave & 1;
    const int wn   = wave >> 1;

    const int rl   = lane >> 3;
    const int sc   = lane & 7;
    const int coff = (sc ^ rl) * 8;

    const unsigned short* hrow[4];
    const unsigned short* w2row[4];
#pragma unroll
    for (int s = 0; s < 4; ++s) {
        const int lr = wave * 32 + s * 8 + rl;
        hrow[s]  = hbuf + (size_t)(row0 + lr) * H1n + coff;
        w2row[s] = w2b + (size_t)lr * H1n + coff;
    }

    f32x4 acc[4][4];
#pragma unroll
    for (int i = 0; i < 4; ++i)
#pragma unroll
        for (int j = 0; j < 4; ++j)
            acc[i][j] = (f32x4){0.f, 0.f, 0.f, 0.f};

    auto issue = [&](int itk, int pb) {
        const int kk0 = itk * 64;
#pragma unroll
        for (int s = 0; s < 4; ++s) {
            gl2lds16(hrow[s] + kk0, &As[pb][(wave * 32 + s * 8) * 64]);
            gl2lds16(w2row[s] + kk0, &Bs[pb][(wave * 32 + s * 8) * 64]);
        }
    };

    issue(0, 0);

    for (int itk = 0; itk < H1n / 64; ++itk) {
        const int cur = itk & 1;
        drain_all();
        __syncthreads();
        if (itk + 1 < H1n / 64) issue(itk + 1, cur ^ 1);
#pragma unroll
        for (int kt = 0; kt < 2; ++kt) {
            s16x8 af[4], bf[4];
#pragma unroll
            for (int i = 0; i < 4; ++i)
                af[i] = *(const s16x8*)&As[cur][(wm * 64 + i * 16 + ln15) * 64 + (((kt * 4 + q4) ^ (ln15 & 7)) * 8)];
#pragma unroll
            for (int jj = 0; jj < 4; ++jj)
                bf[jj] = *(const s16x8*)&Bs[cur][(wn * 64 + jj * 16 + ln15) * 64 + (((kt * 4 + q4) ^ (ln15 & 7)) * 8)];
#pragma unroll
            for (int i = 0; i < 4; ++i)
#pragma unroll
                for (int jj = 0; jj < 4; ++jj)
                    acc[i][jj] = __builtin_amdgcn_mfma_f32_16x16x32_bf16(af[i], bf[jj], acc[i][jj], 0, 0, 0);
        }
    }

#pragma unroll
    for (int i = 0; i < 4; ++i) {
#pragma unroll
        for (int jj = 0; jj < 4; ++jj) {
            const int e = wn * 64 + jj * 16 + ln15;
            const float bias = b2[e];
#pragma unroll
            for (int rg = 0; rg < 4; ++rg) {
                const int m = wm * 64 + i * 16 + q4 * 4 + rg;
                out[(size_t)(row0 + m) * En + e] = acc[i][jj][rg] + bias;
            }
        }
    }
}

// ---------------- launch ----------------
extern "C" void kernel_launch(void* const* d_in, const int* in_sizes, int n_in,
                              void* d_out, int out_size, void* d_ws, size_t ws_size,
                              hipStream_t stream) {
    const int*   current  = (const int*)d_in[0];
    const float* distance = (const float*)d_in[1];
    const float* masked   = (const float*)d_in[2];
    const float* encoded  = (const float*)d_in[3];
    const float* w1       = (const float*)d_in[4];
    const float* b1       = (const float*)d_in[5];
    const float* w2       = (const float*)d_in[6];
    const float* b2       = (const float*)d_in[7];
    float* out = (float*)d_out;

    char* ws = (char*)d_ws;
    const size_t OFF_IDX  = 0;                          // 64000*10*4   = 2,560,000
    const size_t OFF_ENCB = 2560000;                    // 8,192,000*2  = 16,384,000
    const size_t OFF_MEAN = OFF_ENCB + 16384000;        // 64000*128*2  = 16,384,000
    const size_t OFF_W1B  = OFF_MEAN + 16384000;        // 819200*2     = 1,638,400
    const size_t OFF_W2B  = OFF_W1B + 1638400;          // 81920*2      = 163,840
    const size_t OFF_H    = OFF_W2B + 163840;           // 64000*640*2  = 81,920,000
    int*            idxb   = (int*)(ws + OFF_IDX);
    unsigned short* encb   = (unsigned short*)(ws + OFF_ENCB);
    unsigned short* meanbb = (unsigned short*)(ws + OFF_MEAN);
    unsigned short* w1b    = (unsigned short*)(ws + OFF_W1B);
    unsigned short* w2b    = (unsigned short*)(ws + OFF_W2B);
    unsigned short* hbuf   = (unsigned short*)(ws + OFF_H);

    convw_kernel<<<(Bn * Nn * En / 4 + 255) / 256, 256, 0, stream>>>(encoded, w1, w2, encb, w1b, w2b);
    topk_kernel<<<Mn / 4, 256, 0, stream>>>(current, distance, masked, idxb);
    mean_kernel<<<Mn / 2, 256, 0, stream>>>(encb, idxb, meanbb);
    gemm1_kernel<<<2504, 256, 0, stream>>>(encb, meanbb, idxb, w1b, b1, hbuf);
    gemm2_kernel<<<Mn / 128, 256, 0, stream>>>(hbuf, w2b, b2, out);
}

// Round 5
// 484.109 us; speedup vs baseline: 1.5511x; 1.1481x over previous
//
#include <hip/hip_runtime.h>
#include <cstdint>
#include <cstddef>

#define Bn   128
#define Rn   500
#define Nn   500
#define Kn   10
#define En   128
#define H1n  640
#define KEn  1280
#define Mn   (Bn * Rn)   // 64000 rows

typedef short s16x8 __attribute__((ext_vector_type(8)));
typedef float f32x4 __attribute__((ext_vector_type(4)));

// fp32 -> bf16 round-to-nearest-even (finite inputs)
__device__ __forceinline__ unsigned short f2bf(float x) {
    union { float f; unsigned int u; } v; v.f = x;
    unsigned int r = v.u + 0x7fffu + ((v.u >> 16) & 1u);
    return (unsigned short)(r >> 16);
}
__device__ __forceinline__ float bf2f(unsigned short u) {
    union { unsigned int u; float f; } v; v.u = ((unsigned int)u) << 16;
    return v.f;
}
// async 16B global->LDS (wave-uniform LDS base + lane*16)
__device__ __forceinline__ void gl2lds16(const void* g, void* l) {
    __builtin_amdgcn_global_load_lds(
        (const __attribute__((address_space(1))) unsigned int*)g,
        (__attribute__((address_space(3))) unsigned int*)l, 16, 0, 0);
}
// explicit full drain before every barrier: DMAs landed + LDS reads consumed.
// dbuf correctness must not depend on compiler-implicit barrier waits (R3 raced).
__device__ __forceinline__ void drain_all() {
    asm volatile("s_waitcnt vmcnt(0) lgkmcnt(0)" ::: "memory");
}

// ---------------- kernel 1: fp32 -> bf16 conversions (encoded, w1, w2) ----------------
__global__ void convw_kernel(const float* __restrict__ enc, const float* __restrict__ w1,
                             const float* __restrict__ w2,
                             unsigned short* __restrict__ encb, unsigned short* __restrict__ w1b,
                             unsigned short* __restrict__ w2b) {
    int i = blockIdx.x * 256 + threadIdx.x;   // float4 group index
    if (i < (Bn * Nn * En) / 4) {
        float4 v = ((const float4*)enc)[i];
        ushort4 o; o.x = f2bf(v.x); o.y = f2bf(v.y); o.z = f2bf(v.z); o.w = f2bf(v.w);
        ((ushort4*)encb)[i] = o;
    }
    if (i < (H1n * KEn) / 4) {
        float4 v = ((const float4*)w1)[i];
        ushort4 o; o.x = f2bf(v.x); o.y = f2bf(v.y); o.z = f2bf(v.z); o.w = f2bf(v.w);
        ((ushort4*)w1b)[i] = o;
    }
    if (i < (En * H1n) / 4) {
        float4 v = ((const float4*)w2)[i];
        ushort4 o; o.x = f2bf(v.x); o.y = f2bf(v.y); o.z = f2bf(v.z); o.w = f2bf(v.w);
        ((ushort4*)w2b)[i] = o;
    }
}

// ---------------- kernel 2: fused top-K + pad-avg mean ----------------
// One wave per (b,r) row. Top-10 via u64 (bits(dist),idx) min-reduction (stable,
// ascending; +inf -> pad id N). Winners are wave-uniform, so the same wave then
// accumulates the mean of the valid gathered embeddings (u32 = 2 bf16 per lane).
__global__ __launch_bounds__(256) void select_kernel(const int* __restrict__ current,
                            const float* __restrict__ distance,
                            const float* __restrict__ masked,
                            const unsigned short* __restrict__ encb,
                            int* __restrict__ idx_out,
                            unsigned short* __restrict__ meanbb) {
    const int row  = blockIdx.x * 4 + (threadIdx.x >> 6);
    const int lane = threadIdx.x & 63;
    const int b    = row / Rn;
    const int cur  = current[row];
    const unsigned int* drow = (const unsigned int*)(distance + ((size_t)b * Nn + cur) * Nn);
    const unsigned int* mrow = (const unsigned int*)(masked + (size_t)row * Nn);

    unsigned long long key[8];
#pragma unroll
    for (int i = 0; i < 8; ++i) {
        int nn = lane + 64 * i;
        unsigned int fb = 0x7F800000u;            // +inf
        if (nn < Nn) {
            unsigned int m = mrow[nn];
            unsigned int d = drow[nn];
            fb = (m == 0xFF800000u) ? 0x7F800000u : d;   // visited -> +inf
        }
        key[i] = ((unsigned long long)fb << 32) | (unsigned int)nn;
    }

    int ids[Kn];          // wave-uniform winners (unrolled => static indexing)
    int myid = Nn;        // ids[lane] for lanes 0..9 (for the idx store)
#pragma unroll
    for (int it = 0; it < Kn; ++it) {
        unsigned long long bk = key[0];
#pragma unroll
        for (int i = 1; i < 8; ++i) bk = (key[i] < bk) ? key[i] : bk;
#pragma unroll
        for (int off = 1; off < 64; off <<= 1) {
            unsigned long long ok = __shfl_xor(bk, off);
            bk = (ok < bk) ? ok : bk;
        }
        const int wid = ((bk >> 32) == 0x7F800000u) ? Nn : (int)(bk & 0xffffffffu);
        ids[it] = wid;
        if (lane == it) myid = wid;
#pragma unroll
        for (int i = 0; i < 8; ++i)
            if (key[i] == bk) key[i] = 0x7F800000FFFFFFFFull;  // knock out winner
    }
    if (lane < Kn) idx_out[row * Kn + lane] = myid;

    // ---- mean phase: lane handles embedding dims {2*lane, 2*lane+1} ----
    const unsigned int* encu = (const unsigned int*)(encb + (size_t)b * Nn * En);
    float s0 = 0.f, s1 = 0.f; int cnt = 0;
#pragma unroll
    for (int k = 0; k < Kn; ++k) {
        const int id = ids[k];
        if (id < Nn) {
            unsigned int u = encu[id * (En / 2) + lane];
            s0 += bf2f((unsigned short)(u & 0xffffu));
            s1 += bf2f((unsigned short)(u >> 16));
            cnt++;
        }
    }
    float m0 = 0.f, m1 = 0.f;
    if (cnt > 0) { m0 = s0 / (float)cnt; m1 = s1 / (float)cnt; }
    unsigned int packed = (unsigned int)f2bf(m0) | ((unsigned int)f2bf(m1) << 16);
    ((unsigned int*)meanbb)[(size_t)row * (En / 2) + lane] = packed;
}

// ---------------- kernel 3: GEMM1, fused gather, BK=32 double-buffer ----------------
// Tile 128(M) x 128(H) x 32(K), 40 iters, 1 barrier/iter, 37 KB LDS -> 4 blocks/CU.
__global__ __launch_bounds__(256, 4) void gemm1_kernel(
        const unsigned short* __restrict__ encb, const unsigned short* __restrict__ meanbb,
        const int* __restrict__ idxb, const unsigned short* __restrict__ w1b,
        const float* __restrict__ b1, unsigned short* __restrict__ hbuf) {
    __shared__ alignas(16) unsigned short As[2][128 * 32];   // 2 x 8 KB
    __shared__ alignas(16) unsigned short Bs[2][128 * 32];   // 2 x 8 KB
    __shared__ int idxs[128 * Kn];                           // 5 KB

    // XCD-aware remap: 5 h-blocks of one m-block consecutive per XCD.
    const int p = blockIdx.x;
    const int L = (p & 7) * 313 + (p >> 3);
    if (L >= (Mn / 128) * (H1n / 128)) return;
    const int row0 = (L / 5) * 128;
    const int h0   = (L % 5) * 128;

    const int t    = threadIdx.x;
    const int lane = t & 63;
    const int wave = t >> 6;
    const int ln15 = lane & 15;
    const int q4   = lane >> 4;
    const int wm   = wave & 1;
    const int wn   = wave >> 1;

    // stage idx tile (contiguous 1280 ints)
    for (int i = t; i < 128 * Kn; i += 256) idxs[i] = idxb[row0 * Kn + i];

    // staging geometry: row stride 32 ushorts = 64 B = 4 x 16B chunks.
    // lane -> row rl = lane>>2, slot sc = lane&3; slot sc holds source chunk sc^(rl&3).
    const int rl   = lane >> 2;
    const int sc   = lane & 3;
    const int coff = (sc ^ (rl & 3)) * 8;   // source chunk offset (shorts)

    int lrow[2];
    const unsigned short* encB[2];
    const unsigned short* meanR[2];
    const unsigned short* w1R[2];
#pragma unroll
    for (int s = 0; s < 2; ++s) {
        lrow[s] = wave * 32 + s * 16 + rl;
        const int gr = row0 + lrow[s];
        const int bb = gr / Rn;
        encB[s]  = encb + (size_t)bb * Nn * En;
        meanR[s] = meanbb + (size_t)gr * En + coff;
        w1R[s]   = w1b + (size_t)(h0 + lrow[s]) * KEn + coff;
    }

    f32x4 acc[4][4];
#pragma unroll
    for (int i = 0; i < 4; ++i)
#pragma unroll
        for (int j = 0; j < 4; ++j)
            acc[i][j] = (f32x4){0.f, 0.f, 0.f, 0.f};

    auto issue = [&](int itk, int pb) {
        const int j   = itk >> 2;            // neighbor slot
        const int e0  = (itk & 3) * 32;      // quarter of the embedding row
        const int kk0 = itk * 32;
#pragma unroll
        for (int s = 0; s < 2; ++s) {
            const int id = idxs[lrow[s] * Kn + j];
            const unsigned short* srcA = (id < Nn)
                ? (encB[s] + (size_t)id * En + e0 + coff)
                : (meanR[s] + e0);
            gl2lds16(srcA, &As[pb][(wave * 32 + s * 16) * 32]);
            gl2lds16(w1R[s] + kk0, &Bs[pb][(wave * 32 + s * 16) * 32]);
        }
    };

    drain_all();
    __syncthreads();          // idxs visible
    issue(0, 0);

    for (int itk = 0; itk < KEn / 32; ++itk) {
        const int cur = itk & 1;
        drain_all();          // my DMAs landed + my LDS reads consumed
        __syncthreads();      // everyone's landed/consumed
        if (itk + 1 < KEn / 32) issue(itk + 1, cur ^ 1);
        s16x8 af[4], bf[4];
#pragma unroll
        for (int i = 0; i < 4; ++i) {
            const int r = wm * 64 + i * 16 + ln15;
            af[i] = *(const s16x8*)&As[cur][r * 32 + (q4 ^ (r & 3)) * 8];
        }
#pragma unroll
        for (int jj = 0; jj < 4; ++jj) {
            const int r = wn * 64 + jj * 16 + ln15;
            bf[jj] = *(const s16x8*)&Bs[cur][r * 32 + (q4 ^ (r & 3)) * 8];
        }
#pragma unroll
        for (int i = 0; i < 4; ++i)
#pragma unroll
            for (int jj = 0; jj < 4; ++jj)
                acc[i][jj] = __builtin_amdgcn_mfma_f32_16x16x32_bf16(af[i], bf[jj], acc[i][jj], 0, 0, 0);
    }

    // ---- epilogue: bias + relu + bf16 store ----
#pragma unroll
    for (int i = 0; i < 4; ++i) {
#pragma unroll
        for (int jj = 0; jj < 4; ++jj) {
            const int h = h0 + wn * 64 + jj * 16 + ln15;
            const float bias = b1[h];
#pragma unroll
            for (int rg = 0; rg < 4; ++rg) {
                const int m = wm * 64 + i * 16 + q4 * 4 + rg;
                float vv = acc[i][jj][rg] + bias;
                vv = fmaxf(vv, 0.f);
                hbuf[(size_t)(row0 + m) * H1n + h] = f2bf(vv);
            }
        }
    }
}

// ---------------- kernel 4: GEMM2, BK=32 double-buffer ----------------
__global__ __launch_bounds__(256, 4) void gemm2_kernel(
        const unsigned short* __restrict__ hbuf, const unsigned short* __restrict__ w2b,
        const float* __restrict__ b2, float* __restrict__ out) {
    __shared__ alignas(16) unsigned short As[2][128 * 32];
    __shared__ alignas(16) unsigned short Bs[2][128 * 32];

    const int row0 = blockIdx.x * 128;
    const int t    = threadIdx.x;
    const int lane = t & 63;
    const int wave = t >> 6;
    const int ln15 = lane & 15;
    const int q4   = lane >> 4;
    const int wm   = wave & 1;
    const int wn   = wave >> 1;

    const int rl   = lane >> 2;
    const int sc   = lane & 3;
    const int coff = (sc ^ (rl & 3)) * 8;

    const unsigned short* hrow[2];
    const unsigned short* w2row[2];
#pragma unroll
    for (int s = 0; s < 2; ++s) {
        const int lr = wave * 32 + s * 16 + rl;
        hrow[s]  = hbuf + (size_t)(row0 + lr) * H1n + coff;
        w2row[s] = w2b + (size_t)lr * H1n + coff;
    }

    f32x4 acc[4][4];
#pragma unroll
    for (int i = 0; i < 4; ++i)
#pragma unroll
        for (int j = 0; j < 4; ++j)
            acc[i][j] = (f32x4){0.f, 0.f, 0.f, 0.f};

    auto issue = [&](int itk, int pb) {
        const int kk0 = itk * 32;
#pragma unroll
        for (int s = 0; s < 2; ++s) {
            gl2lds16(hrow[s] + kk0, &As[pb][(wave * 32 + s * 16) * 32]);
            gl2lds16(w2row[s] + kk0, &Bs[pb][(wave * 32 + s * 16) * 32]);
        }
    };

    issue(0, 0);

    for (int itk = 0; itk < H1n / 32; ++itk) {
        const int cur = itk & 1;
        drain_all();
        __syncthreads();
        if (itk + 1 < H1n / 32) issue(itk + 1, cur ^ 1);
        s16x8 af[4], bf[4];
#pragma unroll
        for (int i = 0; i < 4; ++i) {
            const int r = wm * 64 + i * 16 + ln15;
            af[i] = *(const s16x8*)&As[cur][r * 32 + (q4 ^ (r & 3)) * 8];
        }
#pragma unroll
        for (int jj = 0; jj < 4; ++jj) {
            const int r = wn * 64 + jj * 16 + ln15;
            bf[jj] = *(const s16x8*)&Bs[cur][r * 32 + (q4 ^ (r & 3)) * 8];
        }
#pragma unroll
        for (int i = 0; i < 4; ++i)
#pragma unroll
            for (int jj = 0; jj < 4; ++jj)
                acc[i][jj] = __builtin_amdgcn_mfma_f32_16x16x32_bf16(af[i], bf[jj], acc[i][jj], 0, 0, 0);
    }

#pragma unroll
    for (int i = 0; i < 4; ++i) {
#pragma unroll
        for (int jj = 0; jj < 4; ++jj) {
            const int e = wn * 64 + jj * 16 + ln15;
            const float bias = b2[e];
#pragma unroll
            for (int rg = 0; rg < 4; ++rg) {
                const int m = wm * 64 + i * 16 + q4 * 4 + rg;
                out[(size_t)(row0 + m) * En + e] = acc[i][jj][rg] + bias;
            }
        }
    }
}

// ---------------- launch ----------------
extern "C" void kernel_launch(void* const* d_in, const int* in_sizes, int n_in,
                              void* d_out, int out_size, void* d_ws, size_t ws_size,
                              hipStream_t stream) {
    const int*   current  = (const int*)d_in[0];
    const float* distance = (const float*)d_in[1];
    const float* masked   = (const float*)d_in[2];
    const float* encoded  = (const float*)d_in[3];
    const float* w1       = (const float*)d_in[4];
    const float* b1       = (const float*)d_in[5];
    const float* w2       = (const float*)d_in[6];
    const float* b2       = (const float*)d_in[7];
    float* out = (float*)d_out;

    char* ws = (char*)d_ws;
    const size_t OFF_IDX  = 0;                          // 64000*10*4   = 2,560,000
    const size_t OFF_ENCB = 2560000;                    // 8,192,000*2  = 16,384,000
    const size_t OFF_MEAN = OFF_ENCB + 16384000;        // 64000*128*2  = 16,384,000
    const size_t OFF_W1B  = OFF_MEAN + 16384000;        // 819200*2     = 1,638,400
    const size_t OFF_W2B  = OFF_W1B + 1638400;          // 81920*2      = 163,840
    const size_t OFF_H    = OFF_W2B + 163840;           // 64000*640*2  = 81,920,000
    int*            idxb   = (int*)(ws + OFF_IDX);
    unsigned short* encb   = (unsigned short*)(ws + OFF_ENCB);
    unsigned short* meanbb = (unsigned short*)(ws + OFF_MEAN);
    unsigned short* w1b    = (unsigned short*)(ws + OFF_W1B);
    unsigned short* w2b    = (unsigned short*)(ws + OFF_W2B);
    unsigned short* hbuf   = (unsigned short*)(ws + OFF_H);

    convw_kernel<<<(Bn * Nn * En / 4 + 255) / 256, 256, 0, stream>>>(encoded, w1, w2, encb, w1b, w2b);
    select_kernel<<<Mn / 4, 256, 0, stream>>>(current, distance, masked, encb, idxb, meanbb);
    gemm1_kernel<<<2504, 256, 0, stream>>>(encb, meanbb, idxb, w1b, b1, hbuf);
    gemm2_kernel<<<Mn / 128, 256, 0, stream>>>(hbuf, w2b, b2, out);
}